// Round 7
// baseline (1717.310 us; speedup 1.0000x reference)
//
#include <hip/hip_runtime.h>
#include <math.h>

typedef _Float16 f16;
typedef _Float16 f16x8 __attribute__((ext_vector_type(8)));
typedef float f32x4 __attribute__((ext_vector_type(4)));

#define NSTEP 128
#define FEAT  127
#define BLK_B 16
#define NBLOCK 256
#define NTHREADS 512

__device__ __forceinline__ float sigf(float x) { return 1.0f / (1.0f + __expf(-x)); }
__device__ __forceinline__ float tanh_(float x) { return 1.0f - 2.0f / (1.0f + __expf(2.0f * x)); }

// Barrier that only guarantees LDS visibility: no vmcnt(0) drain.
__device__ __forceinline__ void sync_lds() {
    asm volatile("s_waitcnt lgkmcnt(0)" ::: "memory");
    __builtin_amdgcn_s_barrier();
    asm volatile("" ::: "memory");
}

#define PIN(v) asm volatile("" : "+v"(v))

// Load one MFMA B-fragment directly from the f32 weight matrix.
__device__ __forceinline__ f16x8 load_wfrag(const float* __restrict__ W, int n, int k) {
    const float* p = W + n * 128 + k;
    f16x8 r;
#pragma unroll
    for (int j = 0; j < 8; ++j) r[j] = (f16)p[j];
    return r;
}

// 16-lane row sum via DPP row_shr cascade; result valid at col==15.
__device__ __forceinline__ float row16_sum(float v) {
    int t;
    t = __builtin_amdgcn_update_dpp(0, __float_as_int(v), 0x118, 0xf, 0xf, true);
    v += __int_as_float(t);
    t = __builtin_amdgcn_update_dpp(0, __float_as_int(v), 0x114, 0xf, 0xf, true);
    v += __int_as_float(t);
    t = __builtin_amdgcn_update_dpp(0, __float_as_int(v), 0x112, 0xf, 0xf, true);
    v += __int_as_float(t);
    t = __builtin_amdgcn_update_dpp(0, __float_as_int(v), 0x111, 0xf, 0xf, true);
    v += __int_as_float(t);
    return v;
}

// w_ih1 fragment slot in dynamic LDS: [wave:8][g:4][ks:4][lane:64] f16x8
// = 8192 slots * 16B = 131072 B exactly (ONE matrix -- capacity-checked).
#define LWIDX(wv, g, ks, ln) (((((wv) * 4 + (g)) * 4 + (ks)) * 64) + (ln))

// ============ Merged kernel: iteration t = L0 step t + L1 step t-1 ===========
// One barrier per iteration; the two recurrences' serial chains overlap.
// Weights: wih0,whh0,whh1 register-pinned (192); wih1 streamed from LDS.
__global__ __launch_bounds__(NTHREADS, 2) void lstm_merged(
    const float* __restrict__ nf,    const float* __restrict__ tgt,
    const float* __restrict__ w_ih0, const float* __restrict__ w_hh0,
    const float* __restrict__ b_ih0, const float* __restrict__ b_hh0,
    const float* __restrict__ w_ih1, const float* __restrict__ w_hh1,
    const float* __restrict__ b_ih1, const float* __restrict__ b_hh1,
    const float* __restrict__ w_out, const float* __restrict__ b_out,
    float* __restrict__ out)
{
    extern __shared__ __align__(16) f16 dynlds[];            // 128KB: w_ih1 only
    __shared__ __align__(16) f16 bufX[2][16][152];
    __shared__ __align__(16) f16 bufH0[2][16][152];
    __shared__ __align__(16) f16 bufH1[2][16][152];
    __shared__ float outp[2][8][16];

    const int tid  = threadIdx.x;
    const int wave = tid >> 6;
    const int lane = tid & 63;
    const int col  = lane & 15;
    const int quad = lane >> 4;
    const int b0   = blockIdx.x * BLK_B;
    const int u    = wave * 16 + col;
    const f32x4 zz = {0.f, 0.f, 0.f, 0.f};

    f16x8* lwp = (f16x8*)dynlds;
    const f16x8* lw = (const f16x8*)dynlds;

    // ---- prologue ----
    for (int i = tid; i < 2 * 16 * 152; i += NTHREADS) {
        (&bufH0[0][0][0])[i] = (f16)0.0f;
        (&bufH1[0][0][0])[i] = (f16)0.0f;
    }

    float bias0[4], bias1[4];
#pragma unroll
    for (int g = 0; g < 4; ++g) {
        bias0[g] = b_ih0[g * 128 + u] + b_hh0[g * 128 + u];
        bias1[g] = b_ih1[g * 128 + u] + b_hh1[g * 128 + u];
    }
    const float wo_u = w_out[u];
    const float bout = b_out[0];

    // L0 weights + L1 h-weights -> registers (192 VGPR-equivalents, pinned)
    f16x8 wih0[4][4], whh0[4][4], whh1[4][4];
#pragma unroll
    for (int g = 0; g < 4; ++g)
#pragma unroll
        for (int ks = 0; ks < 4; ++ks) {
            wih0[g][ks] = load_wfrag(w_ih0, g * 128 + u, ks * 32 + quad * 8);
            whh0[g][ks] = load_wfrag(w_hh0, g * 128 + u, ks * 32 + quad * 8);
            whh1[g][ks] = load_wfrag(w_hh1, g * 128 + u, ks * 32 + quad * 8);
            PIN(wih0[g][ks]);
            PIN(whh0[g][ks]);
            PIN(whh1[g][ks]);
        }

    // w_ih1 -> dynamic LDS (each lane writes exactly its own 16 slots)
#pragma unroll
    for (int g = 0; g < 4; ++g)
#pragma unroll
        for (int ks = 0; ks < 4; ++ks)
            lwp[LWIDX(wave, g, ks, lane)] = load_wfrag(w_ih1, g * 128 + u, ks * 32 + quad * 8);

    // streaming x prefetch pointers, starting at x(2)
    const float* px[2][2];
    int pxs[2][2];
#pragma unroll
    for (int rr = 0; rr < 2; ++rr) {
        const long rowg = b0 + wave * 2 + rr;
#pragma unroll
        for (int h = 0; h < 2; ++h) {
            const int k = lane + 64 * h;
            if (k < FEAT) { px[rr][h] = nf + (rowg * NSTEP + 2) * FEAT + k; pxs[rr][h] = FEAT; }
            else          { px[rr][h] = tgt + rowg * NSTEP + 1;             pxs[rr][h] = 1; }
        }
    }

    f32x4 c0 = {0.f, 0.f, 0.f, 0.f};
    f32x4 c1 = {0.f, 0.f, 0.f, 0.f};

    // stage x(0); prefetch x(1) into xb1
    float xb0[2][2], xb1[2][2];
#pragma unroll
    for (int rr = 0; rr < 2; ++rr) {
        const int row = wave * 2 + rr;
        const long gbt = (long)(b0 + row) * NSTEP;
#pragma unroll
        for (int h = 0; h < 2; ++h) {
            const int k = lane + 64 * h;
            bufX[0][row][k] = (f16)((k < FEAT) ? nf[gbt * FEAT + k] : 0.0f);
            xb1[rr][h] = (k < FEAT) ? nf[(gbt + 1) * FEAT + k] : tgt[gbt];
        }
    }
    sync_lds();

    // ---- one merged iteration ----
    auto iter = [&](int t, int pa, float (&xIssue)[2][2], float (&xWrite)[2][2]) {
        const int wb = pa ^ 1;
        const bool hasL0 = (t < NSTEP);
        const bool hasL1 = (t >= 1);

        // h0(t-1) fragments: L0 h-state AND L1 x-input (shared read)
        f16x8 ah[4];
#pragma unroll
        for (int ks = 0; ks < 4; ++ks)
            ah[ks] = *(const f16x8*)&bufH0[pa][col][ks * 32 + quad * 8];

        // ---------------- layer 0, step t ----------------
        if (hasL0) {
            if (t + 2 < NSTEP) {
#pragma unroll
                for (int rr = 0; rr < 2; ++rr)
#pragma unroll
                    for (int h = 0; h < 2; ++h) {
                        xIssue[rr][h] = *px[rr][h];
                        px[rr][h] += pxs[rr][h];
                    }
            }

            f16x8 ax[4];
#pragma unroll
            for (int ks = 0; ks < 4; ++ks)
                ax[ks] = *(const f16x8*)&bufX[pa][col][ks * 32 + quad * 8];

            f32x4 accx[4], acch[4];
#pragma unroll
            for (int g = 0; g < 4; ++g) {
                f32x4 bv = {bias0[g], bias0[g], bias0[g], bias0[g]};
                accx[g] = __builtin_amdgcn_mfma_f32_16x16x32_f16(ax[0], wih0[g][0], bv, 0, 0, 0);
                acch[g] = __builtin_amdgcn_mfma_f32_16x16x32_f16(ah[0], whh0[g][0], zz, 0, 0, 0);
            }
#pragma unroll
            for (int ks = 1; ks < 4; ++ks)
#pragma unroll
                for (int g = 0; g < 4; ++g) {
                    accx[g] = __builtin_amdgcn_mfma_f32_16x16x32_f16(ax[ks], wih0[g][ks], accx[g], 0, 0, 0);
                    acch[g] = __builtin_amdgcn_mfma_f32_16x16x32_f16(ah[ks], whh0[g][ks], acch[g], 0, 0, 0);
                }

            float h0n[4];
#pragma unroll
            for (int r = 0; r < 4; ++r) {
                const float ig = sigf(accx[0][r] + acch[0][r]);
                const float fg = sigf(accx[1][r] + acch[1][r]);
                const float gg = tanh_(accx[2][r] + acch[2][r]);
                const float og = sigf(accx[3][r] + acch[3][r]);
                const float cn = fg * c0[r] + ig * gg;
                c0[r] = cn;
                h0n[r] = og * tanh_(cn);
            }
#pragma unroll
            for (int r = 0; r < 4; ++r)
                bufH0[wb][quad * 4 + r][u] = (f16)h0n[r];
        }

        // ---------------- layer 1, step t-1 ----------------
        if (hasL1) {
            f16x8 ah1[4];
#pragma unroll
            for (int ks = 0; ks < 4; ++ks)
                ah1[ks] = *(const f16x8*)&bufH1[pa][col][ks * 32 + quad * 8];

            // split chains exactly as R5 step1 (bit-identical op sequence):
            // accx: bias-init, x-part = ah (h0) x wih1 (streamed from LDS)
            // acch: zero-init, h-part = ah1 x whh1 (registers)
            f32x4 accx[4], acch[4];
            {
                f16x8 w0 = lw[LWIDX(wave, 0, 0, lane)];
                f16x8 w1 = lw[LWIDX(wave, 1, 0, lane)];
                f16x8 w2 = lw[LWIDX(wave, 2, 0, lane)];
                f16x8 w3 = lw[LWIDX(wave, 3, 0, lane)];
                f32x4 bv0_ = {bias1[0], bias1[0], bias1[0], bias1[0]};
                f32x4 bv1_ = {bias1[1], bias1[1], bias1[1], bias1[1]};
                f32x4 bv2_ = {bias1[2], bias1[2], bias1[2], bias1[2]};
                f32x4 bv3_ = {bias1[3], bias1[3], bias1[3], bias1[3]};
                accx[0] = __builtin_amdgcn_mfma_f32_16x16x32_f16(ah[0], w0, bv0_, 0, 0, 0);
                accx[1] = __builtin_amdgcn_mfma_f32_16x16x32_f16(ah[0], w1, bv1_, 0, 0, 0);
                accx[2] = __builtin_amdgcn_mfma_f32_16x16x32_f16(ah[0], w2, bv2_, 0, 0, 0);
                accx[3] = __builtin_amdgcn_mfma_f32_16x16x32_f16(ah[0], w3, bv3_, 0, 0, 0);
            }
#pragma unroll
            for (int g = 0; g < 4; ++g)
                acch[g] = __builtin_amdgcn_mfma_f32_16x16x32_f16(ah1[0], whh1[g][0], zz, 0, 0, 0);
#pragma unroll
            for (int ks = 1; ks < 4; ++ks) {
                f16x8 w0 = lw[LWIDX(wave, 0, ks, lane)];
                f16x8 w1 = lw[LWIDX(wave, 1, ks, lane)];
                f16x8 w2 = lw[LWIDX(wave, 2, ks, lane)];
                f16x8 w3 = lw[LWIDX(wave, 3, ks, lane)];
                accx[0] = __builtin_amdgcn_mfma_f32_16x16x32_f16(ah[ks], w0, accx[0], 0, 0, 0);
                accx[1] = __builtin_amdgcn_mfma_f32_16x16x32_f16(ah[ks], w1, accx[1], 0, 0, 0);
                accx[2] = __builtin_amdgcn_mfma_f32_16x16x32_f16(ah[ks], w2, accx[2], 0, 0, 0);
                accx[3] = __builtin_amdgcn_mfma_f32_16x16x32_f16(ah[ks], w3, accx[3], 0, 0, 0);
#pragma unroll
                for (int g = 0; g < 4; ++g)
                    acch[g] = __builtin_amdgcn_mfma_f32_16x16x32_f16(ah1[ks], whh1[g][ks], acch[g], 0, 0, 0);
            }

            float h1n[4];
#pragma unroll
            for (int r = 0; r < 4; ++r) {
                const float ig = sigf(accx[0][r] + acch[0][r]);
                const float fg = sigf(accx[1][r] + acch[1][r]);
                const float gg = tanh_(accx[2][r] + acch[2][r]);
                const float og = sigf(accx[3][r] + acch[3][r]);
                const float cn = fg * c1[r] + ig * gg;
                c1[r] = cn;
                h1n[r] = og * tanh_(cn);
            }
#pragma unroll
            for (int r = 0; r < 4; ++r)
                bufH1[wb][quad * 4 + r][u] = (f16)h1n[r];

            float ps[4];
#pragma unroll
            for (int r = 0; r < 4; ++r) ps[r] = row16_sum(h1n[r] * wo_u);
            if (col == 15) {
#pragma unroll
                for (int r = 0; r < 4; ++r) outp[pa][wave][quad * 4 + r] = ps[r];
            }
        }

        // stage x(t+1) (loaded two iterations ago)
        if (t + 1 < NSTEP) {
#pragma unroll
            for (int rr = 0; rr < 2; ++rr)
#pragma unroll
                for (int h = 0; h < 2; ++h)
                    bufX[wb][wave * 2 + rr][lane + 64 * h] = (f16)xWrite[rr][h];
        }

        sync_lds();

        if (hasL1 && tid < 16) {
            float s = bout;
#pragma unroll
            for (int w = 0; w < 8; ++w) s += outp[pa][w][tid];
            out[(long)(b0 + tid) * NSTEP + (t - 1)] = sigf(s);
        }
    };

    for (int t2 = 0; t2 <= NSTEP; t2 += 2) {
        iter(t2, 0, xb0, xb1);
        if (t2 + 1 <= NSTEP)
            iter(t2 + 1, 1, xb1, xb0);
    }
}

// ============ Fallback: R5 two-phase fused kernel (needs d_ws) ===============
__global__ __launch_bounds__(NTHREADS, 2) void lstm_fused(
    const float* __restrict__ nf,    const float* __restrict__ tgt,
    const float* __restrict__ w_ih0, const float* __restrict__ w_hh0,
    const float* __restrict__ b_ih0, const float* __restrict__ b_hh0,
    const float* __restrict__ w_ih1, const float* __restrict__ w_hh1,
    const float* __restrict__ b_ih1, const float* __restrict__ b_hh1,
    const float* __restrict__ w_out, const float* __restrict__ b_out,
    f16* __restrict__ h0g, float* __restrict__ out)
{
    __shared__ __align__(16) f16 bufA[2][16][152];
    __shared__ __align__(16) f16 bufB[2][16][152];
    __shared__ float outp[2][8][16];

    const int tid  = threadIdx.x;
    const int wave = tid >> 6;
    const int lane = tid & 63;
    const int col  = lane & 15;
    const int quad = lane >> 4;
    const int b0   = blockIdx.x * BLK_B;
    const int u    = wave * 16 + col;
    const f32x4 zz = {0.f, 0.f, 0.f, 0.f};

    {
        for (int i = tid; i < 2 * 16 * 152; i += NTHREADS)
            (&bufB[0][0][0])[i] = (f16)0.0f;

        f32x4 bv0[4];
#pragma unroll
        for (int g = 0; g < 4; ++g) {
            const float b = b_ih0[g * 128 + u] + b_hh0[g * 128 + u];
            bv0[g] = (f32x4){b, b, b, b};
        }

        f16x8 wih0[4][4], whh0[4][4];
#pragma unroll
        for (int g = 0; g < 4; ++g)
#pragma unroll
            for (int ks = 0; ks < 4; ++ks) {
                wih0[g][ks] = load_wfrag(w_ih0, g * 128 + u, ks * 32 + quad * 8);
                whh0[g][ks] = load_wfrag(w_hh0, g * 128 + u, ks * 32 + quad * 8);
                PIN(wih0[g][ks]);
                PIN(whh0[g][ks]);
            }

        const float* px[2][2];
        int pxs[2][2];
#pragma unroll
        for (int rr = 0; rr < 2; ++rr) {
            const long rowg = b0 + wave * 2 + rr;
#pragma unroll
            for (int h = 0; h < 2; ++h) {
                const int k = lane + 64 * h;
                if (k < FEAT) { px[rr][h] = nf + (rowg * NSTEP + 2) * FEAT + k; pxs[rr][h] = FEAT; }
                else          { px[rr][h] = tgt + rowg * NSTEP + 1;             pxs[rr][h] = 1; }
            }
        }

        f16* hp = h0g + (long)(b0 + quad * 4) * NSTEP * 128 + u;
        f32x4 c0 = {0.f, 0.f, 0.f, 0.f};

#pragma unroll
        for (int rr = 0; rr < 2; ++rr) {
            const int row = wave * 2 + rr;
            const long gbt = (long)(b0 + row) * NSTEP;
#pragma unroll
            for (int h = 0; h < 2; ++h) {
                const int k = lane + 64 * h;
                bufA[0][row][k] = (f16)((k < FEAT) ? nf[gbt * FEAT + k] : 0.0f);
            }
        }

        float xb0[2][2], xb1[2][2];
#pragma unroll
        for (int rr = 0; rr < 2; ++rr) {
            const long rowg = b0 + wave * 2 + rr;
#pragma unroll
            for (int h = 0; h < 2; ++h) {
                const int k = lane + 64 * h;
                xb1[rr][h] = (k < FEAT) ? nf[(rowg * NSTEP + 1) * FEAT + k]
                                        : tgt[rowg * NSTEP];
            }
        }
        sync_lds();

        auto step0 = [&](int t, int pa, float (&xIssue)[2][2], float (&xWrite)[2][2]) {
            const int wb = pa ^ 1;
            if (t + 2 < NSTEP) {
#pragma unroll
                for (int rr = 0; rr < 2; ++rr)
#pragma unroll
                    for (int h = 0; h < 2; ++h) {
                        xIssue[rr][h] = *px[rr][h];
                        px[rr][h] += pxs[rr][h];
                    }
            }
            f16x8 ax[4], ah[4];
#pragma unroll
            for (int ks = 0; ks < 4; ++ks) {
                ax[ks] = *(const f16x8*)&bufA[pa][col][ks * 32 + quad * 8];
                ah[ks] = *(const f16x8*)&bufB[pa][col][ks * 32 + quad * 8];
            }
            f32x4 accx[4], acch[4];
#pragma unroll
            for (int g = 0; g < 4; ++g) {
                accx[g] = __builtin_amdgcn_mfma_f32_16x16x32_f16(ax[0], wih0[g][0], bv0[g], 0, 0, 0);
                acch[g] = __builtin_amdgcn_mfma_f32_16x16x32_f16(ah[0], whh0[g][0], zz, 0, 0, 0);
            }
#pragma unroll
            for (int ks = 1; ks < 4; ++ks)
#pragma unroll
                for (int g = 0; g < 4; ++g) {
                    accx[g] = __builtin_amdgcn_mfma_f32_16x16x32_f16(ax[ks], wih0[g][ks], accx[g], 0, 0, 0);
                    acch[g] = __builtin_amdgcn_mfma_f32_16x16x32_f16(ah[ks], whh0[g][ks], acch[g], 0, 0, 0);
                }
            float h0n[4];
#pragma unroll
            for (int r = 0; r < 4; ++r) {
                const float ig = sigf(accx[0][r] + acch[0][r]);
                const float fg = sigf(accx[1][r] + acch[1][r]);
                const float gg = tanh_(accx[2][r] + acch[2][r]);
                const float og = sigf(accx[3][r] + acch[3][r]);
                const float cn = fg * c0[r] + ig * gg;
                c0[r] = cn;
                h0n[r] = og * tanh_(cn);
            }
#pragma unroll
            for (int r = 0; r < 4; ++r) {
                bufB[wb][quad * 4 + r][u] = (f16)h0n[r];
                hp[r * (NSTEP * 128)] = (f16)h0n[r];
            }
            hp += 128;
            if (t + 1 < NSTEP) {
#pragma unroll
                for (int rr = 0; rr < 2; ++rr)
#pragma unroll
                    for (int h = 0; h < 2; ++h)
                        bufA[wb][wave * 2 + rr][lane + 64 * h] = (f16)xWrite[rr][h];
            }
            sync_lds();
        };

        for (int t2 = 0; t2 < NSTEP; t2 += 2) {
            step0(t2,     0, xb0, xb1);
            step0(t2 + 1, 1, xb1, xb0);
        }
    }

    __syncthreads();
    for (int i = tid; i < 2 * 16 * 152; i += NTHREADS)
        (&bufA[0][0][0])[i] = (f16)0.0f;
    __syncthreads();

    {
        f32x4 bv1[4];
#pragma unroll
        for (int g = 0; g < 4; ++g) {
            const float b = b_ih1[g * 128 + u] + b_hh1[g * 128 + u];
            bv1[g] = (f32x4){b, b, b, b};
        }
        const float wo_u = w_out[u];
        const float bout = b_out[0];

        f16x8 wih1[4][4], whh1[4][4];
#pragma unroll
        for (int g = 0; g < 4; ++g)
#pragma unroll
            for (int ks = 0; ks < 4; ++ks) {
                wih1[g][ks] = load_wfrag(w_ih1, g * 128 + u, ks * 32 + quad * 8);
                whh1[g][ks] = load_wfrag(w_hh1, g * 128 + u, ks * 32 + quad * 8);
                PIN(wih1[g][ks]);
                PIN(whh1[g][ks]);
            }

        f32x4 c1 = {0.f, 0.f, 0.f, 0.f};
        const f16* hrow = h0g + (long)(b0 + col) * NSTEP * 128 + quad * 8;
        f16x8 nxA[4], nxB[4];
#pragma unroll
        for (int ks = 0; ks < 4; ++ks)
            nxA[ks] = *(const f16x8*)(hrow + ks * 32);
#pragma unroll
        for (int ks = 0; ks < 4; ++ks)
            nxB[ks] = *(const f16x8*)(hrow + 128 + ks * 32);
        const f16* hnext = hrow + 256;

        auto step1 = [&](int t, int pa, f16x8 (&nxUse)[4]) {
            const int wb = pa ^ 1;
            f16x8 ahv[4];
#pragma unroll
            for (int ks = 0; ks < 4; ++ks)
                ahv[ks] = *(const f16x8*)&bufA[pa][col][ks * 32 + quad * 8];
            f32x4 accx[4], acch[4];
#pragma unroll
            for (int g = 0; g < 4; ++g) {
                accx[g] = __builtin_amdgcn_mfma_f32_16x16x32_f16(nxUse[0], wih1[g][0], bv1[g], 0, 0, 0);
                acch[g] = __builtin_amdgcn_mfma_f32_16x16x32_f16(ahv[0], whh1[g][0], zz, 0, 0, 0);
            }
#pragma unroll
            for (int ks = 1; ks < 4; ++ks)
#pragma unroll
                for (int g = 0; g < 4; ++g) {
                    accx[g] = __builtin_amdgcn_mfma_f32_16x16x32_f16(nxUse[ks], wih1[g][ks], accx[g], 0, 0, 0);
                    acch[g] = __builtin_amdgcn_mfma_f32_16x16x32_f16(ahv[ks], whh1[g][ks], acch[g], 0, 0, 0);
                }
            if (t + 2 < NSTEP) {
#pragma unroll
                for (int ks = 0; ks < 4; ++ks)
                    nxUse[ks] = *(const f16x8*)(hnext + ks * 32);
                hnext += 128;
            }
            float h1n[4];
#pragma unroll
            for (int r = 0; r < 4; ++r) {
                const float ig = sigf(accx[0][r] + acch[0][r]);
                const float fg = sigf(accx[1][r] + acch[1][r]);
                const float gg = tanh_(accx[2][r] + acch[2][r]);
                const float og = sigf(accx[3][r] + acch[3][r]);
                const float cn = fg * c1[r] + ig * gg;
                c1[r] = cn;
                h1n[r] = og * tanh_(cn);
            }
#pragma unroll
            for (int r = 0; r < 4; ++r)
                bufA[wb][quad * 4 + r][u] = (f16)h1n[r];
            float ps[4];
#pragma unroll
            for (int r = 0; r < 4; ++r) ps[r] = row16_sum(h1n[r] * wo_u);
            if (col == 15) {
#pragma unroll
                for (int r = 0; r < 4; ++r) outp[pa][wave][quad * 4 + r] = ps[r];
            }
            sync_lds();
            if (tid < 16) {
                float s = bout;
#pragma unroll
                for (int w = 0; w < 8; ++w) s += outp[pa][w][tid];
                out[(long)(b0 + tid) * NSTEP + t] = sigf(s);
            }
        };

        for (int t2 = 0; t2 < NSTEP; t2 += 2) {
            step1(t2,     0, nxA);
            step1(t2 + 1, 1, nxB);
        }
    }
}

extern "C" void kernel_launch(void* const* d_in, const int* in_sizes, int n_in,
                              void* d_out, int out_size, void* d_ws, size_t ws_size,
                              hipStream_t stream)
{
    const float* nf    = (const float*)d_in[0];
    const float* tgt   = (const float*)d_in[1];
    const float* w_ih0 = (const float*)d_in[2];
    const float* w_hh0 = (const float*)d_in[3];
    const float* b_ih0 = (const float*)d_in[4];
    const float* b_hh0 = (const float*)d_in[5];
    const float* w_ih1 = (const float*)d_in[6];
    const float* w_hh1 = (const float*)d_in[7];
    const float* b_ih1 = (const float*)d_in[8];
    const float* b_hh1 = (const float*)d_in[9];
    const float* w_out = (const float*)d_in[10];
    const float* b_out = (const float*)d_in[11];

    float* out = (float*)d_out;

    static int merged_ok = -1;
    if (merged_ok < 0) {
        hipError_t e = hipFuncSetAttribute(
            reinterpret_cast<const void*>(lstm_merged),
            hipFuncAttributeMaxDynamicSharedMemorySize, 131072);
        merged_ok = (e == hipSuccess) ? 1 : 0;
    }

    const size_t need = (size_t)4096 * 128 * 128 * 2;   // h0g f16 = 128 MB (fallback)
    if (merged_ok) {
        lstm_merged<<<NBLOCK, NTHREADS, 131072, stream>>>(
            nf, tgt, w_ih0, w_hh0, b_ih0, b_hh0,
            w_ih1, w_hh1, b_ih1, b_hh1, w_out, b_out, out);
    } else if (ws_size >= need) {
        f16* h0g = (f16*)d_ws;
        lstm_fused<<<NBLOCK, NTHREADS, 0, stream>>>(
            nf, tgt, w_ih0, w_hh0, b_ih0, b_hh0,
            w_ih1, w_hh1, b_ih1, b_hh1, w_out, b_out, h0g, out);
    }
}

// Round 8
// 1499.278 us; speedup vs baseline: 1.1454x; 1.1454x over previous
//
#include <hip/hip_runtime.h>
#include <math.h>

typedef _Float16 f16;
typedef _Float16 f16x8 __attribute__((ext_vector_type(8)));
typedef float f32x4 __attribute__((ext_vector_type(4)));

#define NSTEP 128
#define FEAT  127
#define BLK_B 16
#define NBLOCK 256
#define NTHREADS 512

__device__ __forceinline__ float sigf(float x) { return 1.0f / (1.0f + __expf(-x)); }
__device__ __forceinline__ float tanh_(float x) { return 1.0f - 2.0f / (1.0f + __expf(2.0f * x)); }

// Barrier that only guarantees LDS visibility: no vmcnt(0) drain.
__device__ __forceinline__ void sync_lds() {
    asm volatile("s_waitcnt lgkmcnt(0)" ::: "memory");
    __builtin_amdgcn_s_barrier();
    asm volatile("" ::: "memory");
}

#define PIN(v) asm volatile("" : "+v"(v))

// Load one MFMA B-fragment directly from the f32 weight matrix.
__device__ __forceinline__ f16x8 load_wfrag(const float* __restrict__ W, int n, int k) {
    const float* p = W + n * 128 + k;
    f16x8 r;
#pragma unroll
    for (int j = 0; j < 8; ++j) r[j] = (f16)p[j];
    return r;
}

// 16-lane row sum via DPP row_shr cascade; result valid at col==15.
__device__ __forceinline__ float row16_sum(float v) {
    int t;
    t = __builtin_amdgcn_update_dpp(0, __float_as_int(v), 0x118, 0xf, 0xf, true);
    v += __int_as_float(t);
    t = __builtin_amdgcn_update_dpp(0, __float_as_int(v), 0x114, 0xf, 0xf, true);
    v += __int_as_float(t);
    t = __builtin_amdgcn_update_dpp(0, __float_as_int(v), 0x112, 0xf, 0xf, true);
    v += __int_as_float(t);
    t = __builtin_amdgcn_update_dpp(0, __float_as_int(v), 0x111, 0xf, 0xf, true);
    v += __int_as_float(t);
    return v;
}

// wih1 fragment slot in dynamic LDS: [wave:8][g:4][ks:4][lane:64] f16x8 = 128KB
#define LWIDX(wv, g, ks, ln) (((((wv) * 4 + (g)) * 4 + (ks)) * 64) + (ln))

// whh1 f16 fragment table in d_ws, same layout: slot (wave,g,ks)*64 + lane.
__global__ void prep_whh1(const float* __restrict__ w_hh1, f16* __restrict__ ws16)
{
    int idx = blockIdx.x * blockDim.x + threadIdx.x;  // 0 .. 65535
    int j    = idx & 7;
    int lane = (idx >> 3) & 63;
    int ks   = (idx >> 9) & 3;
    int g    = (idx >> 11) & 3;
    int wave = (idx >> 13) & 7;
    int n = g * 128 + wave * 16 + (lane & 15);
    int k = ks * 32 + (lane >> 4) * 8 + j;
    ws16[idx] = (f16)w_hh1[n * 128 + k];
}

// ============ Merged kernel: iteration t = L0 step t + L1 step t-1 ===========
// Weights: wih0,whh0 pinned regs (128); wih1 in LDS; whh1 streamed from d_ws
// table (L2-resident) via rotating 2x16-reg landing pA/pB.
__global__ __launch_bounds__(NTHREADS, 2) void lstm_merged(
    const float* __restrict__ nf,    const float* __restrict__ tgt,
    const float* __restrict__ w_ih0, const float* __restrict__ w_hh0,
    const float* __restrict__ b_ih0, const float* __restrict__ b_hh0,
    const float* __restrict__ w_ih1, const float* __restrict__ whh1tab,
    const float* __restrict__ b_ih1, const float* __restrict__ b_hh1,
    const float* __restrict__ w_out, const float* __restrict__ b_out,
    float* __restrict__ out)
{
    extern __shared__ __align__(16) f16 dynlds[];            // 128KB: wih1 only
    __shared__ __align__(16) f16 bufX[2][16][152];
    __shared__ __align__(16) f16 bufH0[2][16][152];
    __shared__ __align__(16) f16 bufH1[2][16][152];
    __shared__ float outp[2][8][16];

    const int tid  = threadIdx.x;
    const int wave = tid >> 6;
    const int lane = tid & 63;
    const int col  = lane & 15;
    const int quad = lane >> 4;
    const int b0   = blockIdx.x * BLK_B;
    const int u    = wave * 16 + col;
    const f32x4 zz = {0.f, 0.f, 0.f, 0.f};

    f16x8* lwp = (f16x8*)dynlds;
    const f16x8* lw = (const f16x8*)dynlds;
    // whh1 stream base for this (wave,lane): frag (g,ks) at wstr[(g*4+ks)*64]
    const f16x8* wstr = (const f16x8*)whh1tab + (wave * 16) * 64 + lane;

    // ---- prologue ----
    for (int i = tid; i < 2 * 16 * 152; i += NTHREADS) {
        (&bufH0[0][0][0])[i] = (f16)0.0f;
        (&bufH1[0][0][0])[i] = (f16)0.0f;
    }

    float bias0[4], bias1[4];
#pragma unroll
    for (int g = 0; g < 4; ++g) {
        bias0[g] = b_ih0[g * 128 + u] + b_hh0[g * 128 + u];
        bias1[g] = b_ih1[g * 128 + u] + b_hh1[g * 128 + u];
    }
    const float wo_u = w_out[u];
    const float bout = b_out[0];

    // L0 weights -> pinned registers (128) -- R5-proven pressure
    f16x8 wih0[4][4], whh0[4][4];
#pragma unroll
    for (int g = 0; g < 4; ++g)
#pragma unroll
        for (int ks = 0; ks < 4; ++ks) {
            wih0[g][ks] = load_wfrag(w_ih0, g * 128 + u, ks * 32 + quad * 8);
            whh0[g][ks] = load_wfrag(w_hh0, g * 128 + u, ks * 32 + quad * 8);
            PIN(wih0[g][ks]);
            PIN(whh0[g][ks]);
        }

    // wih1 -> dynamic LDS (each lane writes exactly its own 16 slots)
#pragma unroll
    for (int g = 0; g < 4; ++g)
#pragma unroll
        for (int ks = 0; ks < 4; ++ks)
            lwp[LWIDX(wave, g, ks, lane)] = load_wfrag(w_ih1, g * 128 + u, ks * 32 + quad * 8);

    // streaming x prefetch pointers, starting at x(2)
    const float* px[2][2];
    int pxs[2][2];
#pragma unroll
    for (int rr = 0; rr < 2; ++rr) {
        const long rowg = b0 + wave * 2 + rr;
#pragma unroll
        for (int h = 0; h < 2; ++h) {
            const int k = lane + 64 * h;
            if (k < FEAT) { px[rr][h] = nf + (rowg * NSTEP + 2) * FEAT + k; pxs[rr][h] = FEAT; }
            else          { px[rr][h] = tgt + rowg * NSTEP + 1;             pxs[rr][h] = 1; }
        }
    }

    f32x4 c0 = {0.f, 0.f, 0.f, 0.f};
    f32x4 c1 = {0.f, 0.f, 0.f, 0.f};

    // stage x(0); prefetch x(1) into xb1
    float xb0[2][2], xb1[2][2];
#pragma unroll
    for (int rr = 0; rr < 2; ++rr) {
        const int row = wave * 2 + rr;
        const long gbt = (long)(b0 + row) * NSTEP;
#pragma unroll
        for (int h = 0; h < 2; ++h) {
            const int k = lane + 64 * h;
            bufX[0][row][k] = (f16)((k < FEAT) ? nf[gbt * FEAT + k] : 0.0f);
            xb1[rr][h] = (k < FEAT) ? nf[(gbt + 1) * FEAT + k] : tgt[gbt];
        }
    }
    sync_lds();

    // one L1 gate: issue next stream group into PNXT, 8-deep chain into h1acc[G]
#define L1_GATE(G, PCUR, PNXT, HASNEXT)                                          \
    {                                                                            \
        if (HASNEXT) {                                                           \
            PNXT[0] = wstr[(((G) + 1) * 4 + 0) * 64];                            \
            PNXT[1] = wstr[(((G) + 1) * 4 + 1) * 64];                            \
            PNXT[2] = wstr[(((G) + 1) * 4 + 2) * 64];                            \
            PNXT[3] = wstr[(((G) + 1) * 4 + 3) * 64];                            \
        }                                                                        \
        f32x4 acc = {bias1[G], bias1[G], bias1[G], bias1[G]};                    \
        acc = __builtin_amdgcn_mfma_f32_16x16x32_f16(ah[0], lw[LWIDX(wave, G, 0, lane)], acc, 0, 0, 0); \
        acc = __builtin_amdgcn_mfma_f32_16x16x32_f16(ah[1], lw[LWIDX(wave, G, 1, lane)], acc, 0, 0, 0); \
        acc = __builtin_amdgcn_mfma_f32_16x16x32_f16(ah[2], lw[LWIDX(wave, G, 2, lane)], acc, 0, 0, 0); \
        acc = __builtin_amdgcn_mfma_f32_16x16x32_f16(ah[3], lw[LWIDX(wave, G, 3, lane)], acc, 0, 0, 0); \
        acc = __builtin_amdgcn_mfma_f32_16x16x32_f16(ah1[0], PCUR[0], acc, 0, 0, 0); \
        acc = __builtin_amdgcn_mfma_f32_16x16x32_f16(ah1[1], PCUR[1], acc, 0, 0, 0); \
        acc = __builtin_amdgcn_mfma_f32_16x16x32_f16(ah1[2], PCUR[2], acc, 0, 0, 0); \
        acc = __builtin_amdgcn_mfma_f32_16x16x32_f16(ah1[3], PCUR[3], acc, 0, 0, 0); \
        h1acc[G] = acc;                                                          \
    }

    // ---- one merged iteration ----
    auto iter = [&](int t, int pa, float (&xIssue)[2][2], float (&xWrite)[2][2]) {
        const int wb = pa ^ 1;
        const bool hasL0 = (t < NSTEP);
        const bool hasL1 = (t >= 1);

        // stream group g=0 issued at iteration start (slack = whole L0 section)
        f16x8 pA[4], pB[4];
        if (hasL1) {
            pA[0] = wstr[0 * 64];
            pA[1] = wstr[1 * 64];
            pA[2] = wstr[2 * 64];
            pA[3] = wstr[3 * 64];
        }

        // h0(t-1) fragments: L0 h-state AND L1 x-input (shared read)
        f16x8 ah[4];
#pragma unroll
        for (int ks = 0; ks < 4; ++ks)
            ah[ks] = *(const f16x8*)&bufH0[pa][col][ks * 32 + quad * 8];

        // ---------------- layer 0, step t ----------------
        if (hasL0) {
            if (t + 2 < NSTEP) {
#pragma unroll
                for (int rr = 0; rr < 2; ++rr)
#pragma unroll
                    for (int h = 0; h < 2; ++h) {
                        xIssue[rr][h] = *px[rr][h];
                        px[rr][h] += pxs[rr][h];
                    }
            }

            f16x8 ax[4];
#pragma unroll
            for (int ks = 0; ks < 4; ++ks)
                ax[ks] = *(const f16x8*)&bufX[pa][col][ks * 32 + quad * 8];

            f32x4 accx[4], acch[4];
#pragma unroll
            for (int g = 0; g < 4; ++g) {
                f32x4 bv = {bias0[g], bias0[g], bias0[g], bias0[g]};
                accx[g] = __builtin_amdgcn_mfma_f32_16x16x32_f16(ax[0], wih0[g][0], bv, 0, 0, 0);
                acch[g] = __builtin_amdgcn_mfma_f32_16x16x32_f16(ah[0], whh0[g][0], zz, 0, 0, 0);
            }
#pragma unroll
            for (int ks = 1; ks < 4; ++ks)
#pragma unroll
                for (int g = 0; g < 4; ++g) {
                    accx[g] = __builtin_amdgcn_mfma_f32_16x16x32_f16(ax[ks], wih0[g][ks], accx[g], 0, 0, 0);
                    acch[g] = __builtin_amdgcn_mfma_f32_16x16x32_f16(ah[ks], whh0[g][ks], acch[g], 0, 0, 0);
                }

            float h0n[4];
#pragma unroll
            for (int r = 0; r < 4; ++r) {
                const float ig = sigf(accx[0][r] + acch[0][r]);
                const float fg = sigf(accx[1][r] + acch[1][r]);
                const float gg = tanh_(accx[2][r] + acch[2][r]);
                const float og = sigf(accx[3][r] + acch[3][r]);
                const float cn = fg * c0[r] + ig * gg;
                c0[r] = cn;
                h0n[r] = og * tanh_(cn);
            }
#pragma unroll
            for (int r = 0; r < 4; ++r)
                bufH0[wb][quad * 4 + r][u] = (f16)h0n[r];
        }

        // ---------------- layer 1, step t-1 ----------------
        if (hasL1) {
            f16x8 ah1[4];
#pragma unroll
            for (int ks = 0; ks < 4; ++ks)
                ah1[ks] = *(const f16x8*)&bufH1[pa][col][ks * 32 + quad * 8];

            f32x4 h1acc[4];
            L1_GATE(0, pA, pB, true);   // consume g0, issue g1
            L1_GATE(1, pB, pA, true);   // consume g1, issue g2
            L1_GATE(2, pA, pB, true);   // consume g2, issue g3
            L1_GATE(3, pB, pA, false);  // consume g3

            float h1n[4];
#pragma unroll
            for (int r = 0; r < 4; ++r) {
                const float ig = sigf(h1acc[0][r]);
                const float fg = sigf(h1acc[1][r]);
                const float gg = tanh_(h1acc[2][r]);
                const float og = sigf(h1acc[3][r]);
                const float cn = fg * c1[r] + ig * gg;
                c1[r] = cn;
                h1n[r] = og * tanh_(cn);
            }
#pragma unroll
            for (int r = 0; r < 4; ++r)
                bufH1[wb][quad * 4 + r][u] = (f16)h1n[r];

            float ps[4];
#pragma unroll
            for (int r = 0; r < 4; ++r) ps[r] = row16_sum(h1n[r] * wo_u);
            if (col == 15) {
#pragma unroll
                for (int r = 0; r < 4; ++r) outp[pa][wave][quad * 4 + r] = ps[r];
            }
        }

        // stage x(t+1) (loaded two iterations ago)
        if (t + 1 < NSTEP) {
#pragma unroll
            for (int rr = 0; rr < 2; ++rr)
#pragma unroll
                for (int h = 0; h < 2; ++h)
                    bufX[wb][wave * 2 + rr][lane + 64 * h] = (f16)xWrite[rr][h];
        }

        sync_lds();

        if (hasL1 && tid < 16) {
            float s = bout;
#pragma unroll
            for (int w = 0; w < 8; ++w) s += outp[pa][w][tid];
            out[(long)(b0 + tid) * NSTEP + (t - 1)] = sigf(s);
        }
    };

    for (int t2 = 0; t2 <= NSTEP; t2 += 2) {
        iter(t2, 0, xb0, xb1);
        if (t2 + 1 <= NSTEP)
            iter(t2 + 1, 1, xb1, xb0);
    }
#undef L1_GATE
}

// ============ Fallback: R5 two-phase fused kernel (needs 128MB d_ws) =========
__global__ __launch_bounds__(NTHREADS, 2) void lstm_fused(
    const float* __restrict__ nf,    const float* __restrict__ tgt,
    const float* __restrict__ w_ih0, const float* __restrict__ w_hh0,
    const float* __restrict__ b_ih0, const float* __restrict__ b_hh0,
    const float* __restrict__ w_ih1, const float* __restrict__ w_hh1,
    const float* __restrict__ b_ih1, const float* __restrict__ b_hh1,
    const float* __restrict__ w_out, const float* __restrict__ b_out,
    f16* __restrict__ h0g, float* __restrict__ out)
{
    __shared__ __align__(16) f16 bufA[2][16][152];
    __shared__ __align__(16) f16 bufB[2][16][152];
    __shared__ float outp[2][8][16];

    const int tid  = threadIdx.x;
    const int wave = tid >> 6;
    const int lane = tid & 63;
    const int col  = lane & 15;
    const int quad = lane >> 4;
    const int b0   = blockIdx.x * BLK_B;
    const int u    = wave * 16 + col;
    const f32x4 zz = {0.f, 0.f, 0.f, 0.f};

    {
        for (int i = tid; i < 2 * 16 * 152; i += NTHREADS)
            (&bufB[0][0][0])[i] = (f16)0.0f;

        f32x4 bv0[4];
#pragma unroll
        for (int g = 0; g < 4; ++g) {
            const float b = b_ih0[g * 128 + u] + b_hh0[g * 128 + u];
            bv0[g] = (f32x4){b, b, b, b};
        }

        f16x8 wih0[4][4], whh0[4][4];
#pragma unroll
        for (int g = 0; g < 4; ++g)
#pragma unroll
            for (int ks = 0; ks < 4; ++ks) {
                wih0[g][ks] = load_wfrag(w_ih0, g * 128 + u, ks * 32 + quad * 8);
                whh0[g][ks] = load_wfrag(w_hh0, g * 128 + u, ks * 32 + quad * 8);
                PIN(wih0[g][ks]);
                PIN(whh0[g][ks]);
            }

        const float* px[2][2];
        int pxs[2][2];
#pragma unroll
        for (int rr = 0; rr < 2; ++rr) {
            const long rowg = b0 + wave * 2 + rr;
#pragma unroll
            for (int h = 0; h < 2; ++h) {
                const int k = lane + 64 * h;
                if (k < FEAT) { px[rr][h] = nf + (rowg * NSTEP + 2) * FEAT + k; pxs[rr][h] = FEAT; }
                else          { px[rr][h] = tgt + rowg * NSTEP + 1;             pxs[rr][h] = 1; }
            }
        }

        f16* hp = h0g + (long)(b0 + quad * 4) * NSTEP * 128 + u;
        f32x4 c0 = {0.f, 0.f, 0.f, 0.f};

#pragma unroll
        for (int rr = 0; rr < 2; ++rr) {
            const int row = wave * 2 + rr;
            const long gbt = (long)(b0 + row) * NSTEP;
#pragma unroll
            for (int h = 0; h < 2; ++h) {
                const int k = lane + 64 * h;
                bufA[0][row][k] = (f16)((k < FEAT) ? nf[gbt * FEAT + k] : 0.0f);
            }
        }

        float xb0[2][2], xb1[2][2];
#pragma unroll
        for (int rr = 0; rr < 2; ++rr) {
            const long rowg = b0 + wave * 2 + rr;
#pragma unroll
            for (int h = 0; h < 2; ++h) {
                const int k = lane + 64 * h;
                xb1[rr][h] = (k < FEAT) ? nf[(rowg * NSTEP + 1) * FEAT + k]
                                        : tgt[rowg * NSTEP];
            }
        }
        sync_lds();

        auto step0 = [&](int t, int pa, float (&xIssue)[2][2], float (&xWrite)[2][2]) {
            const int wb = pa ^ 1;
            if (t + 2 < NSTEP) {
#pragma unroll
                for (int rr = 0; rr < 2; ++rr)
#pragma unroll
                    for (int h = 0; h < 2; ++h) {
                        xIssue[rr][h] = *px[rr][h];
                        px[rr][h] += pxs[rr][h];
                    }
            }
            f16x8 ax[4], ah[4];
#pragma unroll
            for (int ks = 0; ks < 4; ++ks) {
                ax[ks] = *(const f16x8*)&bufA[pa][col][ks * 32 + quad * 8];
                ah[ks] = *(const f16x8*)&bufB[pa][col][ks * 32 + quad * 8];
            }
            f32x4 accx[4], acch[4];
#pragma unroll
            for (int g = 0; g < 4; ++g) {
                accx[g] = __builtin_amdgcn_mfma_f32_16x16x32_f16(ax[0], wih0[g][0], bv0[g], 0, 0, 0);
                acch[g] = __builtin_amdgcn_mfma_f32_16x16x32_f16(ah[0], whh0[g][0], zz, 0, 0, 0);
            }
#pragma unroll
            for (int ks = 1; ks < 4; ++ks)
#pragma unroll
                for (int g = 0; g < 4; ++g) {
                    accx[g] = __builtin_amdgcn_mfma_f32_16x16x32_f16(ax[ks], wih0[g][ks], accx[g], 0, 0, 0);
                    acch[g] = __builtin_amdgcn_mfma_f32_16x16x32_f16(ah[ks], whh0[g][ks], acch[g], 0, 0, 0);
                }
            float h0n[4];
#pragma unroll
            for (int r = 0; r < 4; ++r) {
                const float ig = sigf(accx[0][r] + acch[0][r]);
                const float fg = sigf(accx[1][r] + acch[1][r]);
                const float gg = tanh_(accx[2][r] + acch[2][r]);
                const float og = sigf(accx[3][r] + acch[3][r]);
                const float cn = fg * c0[r] + ig * gg;
                c0[r] = cn;
                h0n[r] = og * tanh_(cn);
            }
#pragma unroll
            for (int r = 0; r < 4; ++r) {
                bufB[wb][quad * 4 + r][u] = (f16)h0n[r];
                hp[r * (NSTEP * 128)] = (f16)h0n[r];
            }
            hp += 128;
            if (t + 1 < NSTEP) {
#pragma unroll
                for (int rr = 0; rr < 2; ++rr)
#pragma unroll
                    for (int h = 0; h < 2; ++h)
                        bufA[wb][wave * 2 + rr][lane + 64 * h] = (f16)xWrite[rr][h];
            }
            sync_lds();
        };

        for (int t2 = 0; t2 < NSTEP; t2 += 2) {
            step0(t2,     0, xb0, xb1);
            step0(t2 + 1, 1, xb1, xb0);
        }
    }

    __syncthreads();
    for (int i = tid; i < 2 * 16 * 152; i += NTHREADS)
        (&bufA[0][0][0])[i] = (f16)0.0f;
    __syncthreads();

    {
        f32x4 bv1[4];
#pragma unroll
        for (int g = 0; g < 4; ++g) {
            const float b = b_ih1[g * 128 + u] + b_hh1[g * 128 + u];
            bv1[g] = (f32x4){b, b, b, b};
        }
        const float wo_u = w_out[u];
        const float bout = b_out[0];

        f16x8 wih1[4][4], whh1[4][4];
#pragma unroll
        for (int g = 0; g < 4; ++g)
#pragma unroll
            for (int ks = 0; ks < 4; ++ks) {
                wih1[g][ks] = load_wfrag(w_ih1, g * 128 + u, ks * 32 + quad * 8);
                whh1[g][ks] = load_wfrag(w_hh1, g * 128 + u, ks * 32 + quad * 8);
                PIN(wih1[g][ks]);
                PIN(whh1[g][ks]);
            }

        f32x4 c1 = {0.f, 0.f, 0.f, 0.f};
        const f16* hrow = h0g + (long)(b0 + col) * NSTEP * 128 + quad * 8;
        f16x8 nxA[4], nxB[4];
#pragma unroll
        for (int ks = 0; ks < 4; ++ks)
            nxA[ks] = *(const f16x8*)(hrow + ks * 32);
#pragma unroll
        for (int ks = 0; ks < 4; ++ks)
            nxB[ks] = *(const f16x8*)(hrow + 128 + ks * 32);
        const f16* hnext = hrow + 256;

        auto step1 = [&](int t, int pa, f16x8 (&nxUse)[4]) {
            const int wb = pa ^ 1;
            f16x8 ahv[4];
#pragma unroll
            for (int ks = 0; ks < 4; ++ks)
                ahv[ks] = *(const f16x8*)&bufA[pa][col][ks * 32 + quad * 8];
            f32x4 accx[4], acch[4];
#pragma unroll
            for (int g = 0; g < 4; ++g) {
                accx[g] = __builtin_amdgcn_mfma_f32_16x16x32_f16(nxUse[0], wih1[g][0], bv1[g], 0, 0, 0);
                acch[g] = __builtin_amdgcn_mfma_f32_16x16x32_f16(ahv[0], whh1[g][0], zz, 0, 0, 0);
            }
#pragma unroll
            for (int ks = 1; ks < 4; ++ks)
#pragma unroll
                for (int g = 0; g < 4; ++g) {
                    accx[g] = __builtin_amdgcn_mfma_f32_16x16x32_f16(nxUse[ks], wih1[g][ks], accx[g], 0, 0, 0);
                    acch[g] = __builtin_amdgcn_mfma_f32_16x16x32_f16(ahv[ks], whh1[g][ks], acch[g], 0, 0, 0);
                }
            if (t + 2 < NSTEP) {
#pragma unroll
                for (int ks = 0; ks < 4; ++ks)
                    nxUse[ks] = *(const f16x8*)(hnext + ks * 32);
                hnext += 128;
            }
            float h1n[4];
#pragma unroll
            for (int r = 0; r < 4; ++r) {
                const float ig = sigf(accx[0][r] + acch[0][r]);
                const float fg = sigf(accx[1][r] + acch[1][r]);
                const float gg = tanh_(accx[2][r] + acch[2][r]);
                const float og = sigf(accx[3][r] + acch[3][r]);
                const float cn = fg * c1[r] + ig * gg;
                c1[r] = cn;
                h1n[r] = og * tanh_(cn);
            }
#pragma unroll
            for (int r = 0; r < 4; ++r)
                bufA[wb][quad * 4 + r][u] = (f16)h1n[r];
            float ps[4];
#pragma unroll
            for (int r = 0; r < 4; ++r) ps[r] = row16_sum(h1n[r] * wo_u);
            if (col == 15) {
#pragma unroll
                for (int r = 0; r < 4; ++r) outp[pa][wave][quad * 4 + r] = ps[r];
            }
            sync_lds();
            if (tid < 16) {
                float s = bout;
#pragma unroll
                for (int w = 0; w < 8; ++w) s += outp[pa][w][tid];
                out[(long)(b0 + tid) * NSTEP + t] = sigf(s);
            }
        };

        for (int t2 = 0; t2 < NSTEP; t2 += 2) {
            step1(t2,     0, nxA);
            step1(t2 + 1, 1, nxB);
        }
    }
}

extern "C" void kernel_launch(void* const* d_in, const int* in_sizes, int n_in,
                              void* d_out, int out_size, void* d_ws, size_t ws_size,
                              hipStream_t stream)
{
    const float* nf    = (const float*)d_in[0];
    const float* tgt   = (const float*)d_in[1];
    const float* w_ih0 = (const float*)d_in[2];
    const float* w_hh0 = (const float*)d_in[3];
    const float* b_ih0 = (const float*)d_in[4];
    const float* b_hh0 = (const float*)d_in[5];
    const float* w_ih1 = (const float*)d_in[6];
    const float* w_hh1 = (const float*)d_in[7];
    const float* b_ih1 = (const float*)d_in[8];
    const float* b_hh1 = (const float*)d_in[9];
    const float* w_out = (const float*)d_in[10];
    const float* b_out = (const float*)d_in[11];

    float* out = (float*)d_out;

    static int merged_ok = -1;
    if (merged_ok < 0) {
        hipError_t e = hipFuncSetAttribute(
            reinterpret_cast<const void*>(lstm_merged),
            hipFuncAttributeMaxDynamicSharedMemorySize, 131072);
        merged_ok = (e == hipSuccess) ? 1 : 0;
    }

    if (merged_ok && ws_size >= 131072) {
        f16* wtab = (f16*)d_ws;                        // 128 KB whh1 fragment table
        prep_whh1<<<256, 256, 0, stream>>>(w_hh1, wtab);
        lstm_merged<<<NBLOCK, NTHREADS, 131072, stream>>>(
            nf, tgt, w_ih0, w_hh0, b_ih0, b_hh0,
            w_ih1, (const float*)wtab, b_ih1, b_hh1, w_out, b_out, out);
    } else if (ws_size >= (size_t)4096 * 128 * 128 * 2) {
        f16* h0g = (f16*)d_ws;
        lstm_fused<<<NBLOCK, NTHREADS, 0, stream>>>(
            nf, tgt, w_ih0, w_hh0, b_ih0, b_hh0,
            w_ih1, w_hh1, b_ih1, b_hh1, w_out, b_out, h0g, out);
    }
}